// Round 10
// baseline (405.965 us; speedup 1.0000x reference)
//
#include <hip/hip_runtime.h>
#include <hip/hip_bf16.h>
#include <stdint.h>

#define S_NUM 50000
#define E_NUM 20000
#define NNODE 70000
#define KDIM 128
#define BATCH 8192
#define NEDGE 1000000

#define NRANGE 128            // dst-ranges per graph
#define RSZ 547               // ceil(NNODE / NRANGE)
#define BUCKET_CAP 8448       // per-bucket capacity (mean 7813, sigma 88)
#define RCAP 16672            // per-range padded csr region (>= 8448 + 547*15)
#define CHUNK 8192            // edges per bucket_k block
#define BINCAP 120            // LDS bin capacity

typedef __attribute__((ext_vector_type(8))) short short8;
typedef __attribute__((ext_vector_type(4))) float f32x4;
typedef __attribute__((ext_vector_type(2))) float f32x2;

__device__ __forceinline__ float bf2f(ushort u) {
    union { uint32_t i; float f; } v; v.i = ((uint32_t)u) << 16; return v.f;
}
__device__ __forceinline__ ushort f2bf(float f) {
    union { uint32_t i; float f; } v; v.f = f;
    uint32_t r = v.i + 0x7fffu + ((v.i >> 16) & 1u);
    return (ushort)(r >> 16);
}
// unpack 2 bf16 (packed in uint32) -> f32x2 {lo, hi}
__device__ __forceinline__ f32x2 up2(uint32_t u) {
    union { uint32_t i; float f; } lo, hi;
    lo.i = u << 16; hi.i = u & 0xffff0000u;
    f32x2 r; r.x = lo.f; r.y = hi.f; return r;
}

// ---------------- W prep (+ gbcnt zero): bf16 hi/lo split, swizzled ----------------
__global__ void prepW_k(const float* __restrict__ rW, const float* __restrict__ wW,
                        ushort* __restrict__ ws, int* __restrict__ gbcnt) {
    if (blockIdx.x == 0 && threadIdx.x < 256) gbcnt[threadIdx.x] = 0;
    int i = blockIdx.x * blockDim.x + threadIdx.x;
    if (i >= 6 * 16384) return;
    int m = i >> 14, idx = i & 16383;
    const float* W = (m < 3) ? rW + m * 16384 : wW + (m - 3) * 16384;
    float x = W[idx];
    int k = idx >> 7, c = idx & 127;
    ushort hb = f2bf(x);
    ushort lb = f2bf(x - bf2f(hb));
    int off = ((c * 256 + 2 * k) ^ ((c & 7) << 4)) >> 1;
    ws[(size_t)m * 32768 + off] = hb;
    ws[(size_t)m * 32768 + 16384 + off] = lb;
}

// ---------------- pass 1: bin edges by dst-range, packed (local_dst<<17 | src) -------------
__global__ __launch_bounds__(256) void bucket_k(const int* __restrict__ redge,
                                                const int* __restrict__ wedge,
                                                int* __restrict__ gbcnt,
                                                uint32_t* __restrict__ bpk) {
    __shared__ uint32_t lpk[NRANGE][BINCAP];
    __shared__ int lcnt[NRANGE];
    __shared__ int gbase[NRANGE];
    const int NB = (NEDGE + CHUNK - 1) / CHUNK;
    int bid = blockIdx.x;
    int graph = bid >= NB;
    int cb = graph ? bid - NB : bid;
    const int* eg = graph ? wedge : redge;
    int e0 = cb * CHUNK;
    int nthis = min(CHUNK, NEDGE - e0);
    for (int i = threadIdx.x; i < NRANGE; i += 256) lcnt[i] = 0;
    __syncthreads();
    for (int i = threadIdx.x; i < nthis; i += 256) {
        int s = eg[e0 + i];
        int d = eg[NEDGE + e0 + i];
        int b = d / RSZ;
        uint32_t p = ((uint32_t)(d - b * RSZ) << 17) | (uint32_t)s;
        int slot = atomicAdd(&lcnt[b], 1);
        if (slot < BINCAP) lpk[b][slot] = p;
        else {
            int gs = atomicAdd(&gbcnt[graph * NRANGE + b], 1);
            if (gs < BUCKET_CAP)
                bpk[(size_t)(graph * NRANGE + b) * BUCKET_CAP + gs] = p;
        }
    }
    __syncthreads();
    for (int b = threadIdx.x; b < NRANGE; b += 256) {
        int c = min(lcnt[b], BINCAP);
        lcnt[b] = c;
        gbase[b] = atomicAdd(&gbcnt[graph * NRANGE + b], c);
    }
    __syncthreads();
    for (int b = 0; b < NRANGE; ++b) {
        int c = lcnt[b];
        size_t base = (size_t)(graph * NRANGE + b) * BUCKET_CAP + gbase[b];
        for (int i = threadIdx.x; i < c; i += 256)
            if (gbase[b] + i < BUCKET_CAP) bpk[base + i] = lpk[b][i];
    }
}

// ---------------- pass 2: CSR slice in LDS, 16-padded rows, fixed per-combo regions --------
__global__ __launch_bounds__(256) void build_k(const uint32_t* __restrict__ bpk,
                                               const int* __restrict__ gbcnt,
                                               int* __restrict__ rpb,
                                               int* __restrict__ rpe,
                                               int* __restrict__ csr) {
    __shared__ int lcnt[RSZ];
    __shared__ int lexcl[RSZ];
    __shared__ int pexcl[RSZ];
    __shared__ int lcur[RSZ];
    __shared__ int sliceB[BUCKET_CAP];
    __shared__ int wsum[4];
    __shared__ int s_carry;
    int combo = blockIdx.x;                 // 0..255
    int graph = combo >> 7, grp = combo & (NRANGE - 1);
    int lo = grp * RSZ;
    int rsize = min(RSZ, NNODE - lo);
    int n = min(gbcnt[combo], BUCKET_CAP);
    const uint32_t* bp = bpk + (size_t)combo * BUCKET_CAP;
    int* rpbg = rpb + graph * NNODE;
    int* rpeg = rpe + graph * NNODE;
    int* og = csr + (size_t)combo * RCAP;
    const int rbase = combo * RCAP;
    int tid = threadIdx.x, lane = tid & 63, wid = tid >> 6;

    for (int i = tid; i < rsize; i += 256) lcnt[i] = 0;
    if (tid == 0) s_carry = 0;
    __syncthreads();
    for (int i = tid; i < n; i += 256)
        atomicAdd(&lcnt[bp[i] >> 17], 1);
    __syncthreads();
    // scan 1: real counts -> lexcl
    for (int base = 0; base < rsize; base += 256) {
        int i = base + tid;
        int v = (i < rsize) ? lcnt[i] : 0;
        int incl = v;
        #pragma unroll
        for (int off = 1; off < 64; off <<= 1) {
            int t = __shfl_up(incl, off, 64);
            if (lane >= off) incl += t;
        }
        if (lane == 63) wsum[wid] = incl;
        __syncthreads();
        int carry = s_carry;
        if (wid == 0 && lane < 4) {
            int wv = wsum[lane];
            #pragma unroll
            for (int off = 1; off < 4; off <<= 1) {
                int t = __shfl_up(wv, off, 64);
                if (lane >= off) wv += t;
            }
            wsum[lane] = wv;
        }
        __syncthreads();
        int waveoff = (wid == 0) ? 0 : wsum[wid - 1];
        int excl = carry + waveoff + incl - v;
        if (i < rsize) { lexcl[i] = excl; lcur[i] = excl; }
        __syncthreads();
        if (tid == 0) s_carry = carry + wsum[3];
        __syncthreads();
    }
    if (tid == 0) s_carry = 0;
    __syncthreads();
    // scan 2: padded counts -> pexcl
    for (int base = 0; base < rsize; base += 256) {
        int i = base + tid;
        int v = (i < rsize) ? ((lcnt[i] + 15) & ~15) : 0;
        int incl = v;
        #pragma unroll
        for (int off = 1; off < 64; off <<= 1) {
            int t = __shfl_up(incl, off, 64);
            if (lane >= off) incl += t;
        }
        if (lane == 63) wsum[wid] = incl;
        __syncthreads();
        int carry = s_carry;
        if (wid == 0 && lane < 4) {
            int wv = wsum[lane];
            #pragma unroll
            for (int off = 1; off < 4; off <<= 1) {
                int t = __shfl_up(wv, off, 64);
                if (lane >= off) wv += t;
            }
            wsum[lane] = wv;
        }
        __syncthreads();
        int waveoff = (wid == 0) ? 0 : wsum[wid - 1];
        int excl = carry + waveoff + incl - v;
        if (i < rsize) pexcl[i] = excl;
        __syncthreads();
        if (tid == 0) s_carry = carry + wsum[3];
        __syncthreads();
    }
    for (int i = tid; i < rsize; i += 256) {
        int pc = (lcnt[i] + 15) & ~15;
        rpbg[lo + i] = rbase + pexcl[i];
        rpeg[lo + i] = rbase + pexcl[i] + pc;
    }
    for (int i = tid; i < n; i += 256) {
        uint32_t p = bp[i];
        int slot = atomicAdd(&lcur[p >> 17], 1);
        sliceB[slot] = (int)p;
    }
    __syncthreads();
    for (int i = tid; i < n; i += 256) {
        uint32_t p = (uint32_t)sliceB[i];
        int r = p >> 17;
        og[pexcl[r] + (i - lexcl[r])] = (int)(p & 0x1FFFFu);
    }
    for (int r = tid; r < rsize; r += 256) {
        int c = lcnt[r], pc = (c + 15) & ~15, b = pexcl[r];
        for (int j = c; j < pc; ++j) og[b + j] = NNODE;
    }
}

// ---------------- cvt: featb = bf16([stu; exer]) + sentinel rows + padded cj copies --------
__global__ __launch_bounds__(256) void cvt1_k(const float* __restrict__ stu,
                                              const float* __restrict__ exer,
                                              const float* __restrict__ rcj,
                                              const float* __restrict__ wcj,
                                              uint4* __restrict__ featb,
                                              uint4* __restrict__ fcR,
                                              uint4* __restrict__ fcW,
                                              uint4* __restrict__ pR,
                                              uint4* __restrict__ pW,
                                              float* __restrict__ cjpR,
                                              float* __restrict__ cjpW) {
    const int main = NNODE * 16;           // uint4 per row
    const int total = main + 80 + 2 * (NNODE + 1);
    const uint4 z4 = {0, 0, 0, 0};
    for (int i = blockIdx.x * blockDim.x + threadIdx.x; i < total;
         i += gridDim.x * blockDim.x) {
        if (i < main) {
            int node = i >> 4;
            int qq = i & 15;
            const float4* src = (const float4*)((node < S_NUM)
                                  ? stu + (size_t)node * KDIM
                                  : exer + (size_t)(node - S_NUM) * KDIM);
            float4 a = src[qq * 2];
            float4 b = src[qq * 2 + 1];
            uint4 o;
            o.x = (uint32_t)f2bf(a.x) | ((uint32_t)f2bf(a.y) << 16);
            o.y = (uint32_t)f2bf(a.z) | ((uint32_t)f2bf(a.w) << 16);
            o.z = (uint32_t)f2bf(b.x) | ((uint32_t)f2bf(b.y) << 16);
            o.w = (uint32_t)f2bf(b.z) | ((uint32_t)f2bf(b.w) << 16);
            featb[i] = o;
        } else if (i < main + 80) {
            int j = i - main;
            size_t off = (size_t)NNODE * 16 + (j & 15);
            switch (j >> 4) {
                case 0: featb[off] = z4; break;
                case 1: fcR[off] = z4; break;
                case 2: fcW[off] = z4; break;
                case 3: pR[off] = z4; break;
                default: pW[off] = z4; break;
            }
        } else {
            int k = i - main - 80;
            if (k <= NNODE)  cjpR[k] = (k < NNODE) ? rcj[k] : 0.f;
            else {
                int m = k - (NNODE + 1);
                cjpW[m] = (m < NNODE) ? wcj[m] : 0.f;
            }
        }
    }
}

// ---------------- gather 4 edge-slots of one node into f32x2 accumulators ----------------
template<int USECJ>
__device__ __forceinline__ void gath4(const uint4* __restrict__ fc,
                                      const float* __restrict__ cjg,
                                      const int* __restrict__ csr,
                                      int e, int rowgrp, int c16,
                                      f32x2& a0, f32x2& a1, f32x2& a2, f32x2& a3) {
    int s0 = csr[e + rowgrp];
    int s1 = csr[e + 4 + rowgrp];
    int s2 = csr[e + 8 + rowgrp];
    int s3 = csr[e + 12 + rowgrp];
    uint4 u0 = fc[(size_t)s0 * 16 + c16];
    uint4 u1 = fc[(size_t)s1 * 16 + c16];
    uint4 u2 = fc[(size_t)s2 * 16 + c16];
    uint4 u3 = fc[(size_t)s3 * 16 + c16];
    if (USECJ) {
        float c0 = cjg[s0], c1 = cjg[s1], c2 = cjg[s2], c3 = cjg[s3];
        f32x2 v0 = {c0, c0}, v1 = {c1, c1}, v2 = {c2, c2}, v3 = {c3, c3};
        a0 += v0 * up2(u0.x) + v1 * up2(u1.x) + v2 * up2(u2.x) + v3 * up2(u3.x);
        a1 += v0 * up2(u0.y) + v1 * up2(u1.y) + v2 * up2(u2.y) + v3 * up2(u3.y);
        a2 += v0 * up2(u0.z) + v1 * up2(u1.z) + v2 * up2(u2.z) + v3 * up2(u3.z);
        a3 += v0 * up2(u0.w) + v1 * up2(u1.w) + v2 * up2(u2.w) + v3 * up2(u3.w);
    } else {
        a0 += (up2(u0.x) + up2(u1.x)) + (up2(u2.x) + up2(u3.x));
        a1 += (up2(u0.y) + up2(u1.y)) + (up2(u2.y) + up2(u3.y));
        a2 += (up2(u0.z) + up2(u1.z)) + (up2(u2.z) + up2(u3.z));
        a3 += (up2(u0.w) + up2(u1.w)) + (up2(u2.w) + up2(u3.w));
    }
}

// ---------------- fused agg + GEMM, both graphs ----------------
// Per wave: aggregate 16 consecutive nodes (2 interleaved for MLP) into a 4KB
// XOR-swizzled LDS tile, then 16x128 GEMM (MFMA) reading pre-swizzled W from
// global (L2-hot). out = scal ⊙ ((agg) @ W), scal = ci*cj (mode1) or ci (mode0).
template<int USECJ>
__global__ __launch_bounds__(256) void aggemm_k(const uint4* __restrict__ srcR,
                                                const uint4* __restrict__ srcW,
                                                const float* __restrict__ cjR,
                                                const float* __restrict__ cjW,
                                                const int* __restrict__ rpb,
                                                const int* __restrict__ rpe,
                                                const int* __restrict__ csr,
                                                const ushort* __restrict__ wsR,
                                                const ushort* __restrict__ wsW,
                                                const float* __restrict__ rci,
                                                const float* __restrict__ rcj,
                                                const float* __restrict__ wci,
                                                const float* __restrict__ wcj,
                                                ushort* __restrict__ outR,
                                                ushort* __restrict__ outW,
                                                int mode) {
    __shared__ char stage[4][4096];        // per-wave 16 rows x 128 bf16, swizzled
    const int BPG = (NNODE + 63) / 64;     // 1094
    int graph = blockIdx.x >= BPG;
    int bb = graph ? blockIdx.x - BPG : blockIdx.x;
    const uint4* fc = graph ? srcW : srcR;
    const float* cjg = graph ? cjW : cjR;
    const int* rpbg = rpb + graph * NNODE;
    const int* rpeg = rpe + graph * NNODE;
    const ushort* wsm = graph ? wsW : wsR;
    const float* cia = graph ? wci : rci;
    const float* cja = graph ? wcj : rcj;
    ushort* outB = graph ? outW : outR;

    int wid = threadIdx.x >> 6, lane = threadIdx.x & 63;
    int rowgrp = lane >> 4, c16 = lane & 15;
    int nodebase = bb * 64 + wid * 16;
    char* st = stage[wid];

    // ---- phase 1: aggregate 16 nodes (2 at a time for 8 loads in flight) ----
    for (int nl = 0; nl < 16; nl += 2) {
        int nA = nodebase + nl, nB = nA + 1;
        f32x2 aA0 = {0.f, 0.f}, aA1 = {0.f, 0.f}, aA2 = {0.f, 0.f}, aA3 = {0.f, 0.f};
        f32x2 aB0 = {0.f, 0.f}, aB1 = {0.f, 0.f}, aB2 = {0.f, 0.f}, aB3 = {0.f, 0.f};
        int eA = 0, endA = 0, eB = 0, endB = 0;
        if (nA < NNODE) { eA = rpbg[nA]; endA = rpeg[nA]; }
        if (nB < NNODE) { eB = rpbg[nB]; endB = rpeg[nB]; }
        while (eA < endA || eB < endB) {
            if (eA < endA) {
                gath4<USECJ>(fc, cjg, csr, eA, rowgrp, c16, aA0, aA1, aA2, aA3);
                eA += 16;
            }
            if (eB < endB) {
                gath4<USECJ>(fc, cjg, csr, eB, rowgrp, c16, aB0, aB1, aB2, aB3);
                eB += 16;
            }
        }
        float rA[8] = {aA0.x, aA0.y, aA1.x, aA1.y, aA2.x, aA2.y, aA3.x, aA3.y};
        float rB[8] = {aB0.x, aB0.y, aB1.x, aB1.y, aB2.x, aB2.y, aB3.x, aB3.y};
        #pragma unroll
        for (int j = 0; j < 8; ++j) {
            rA[j] += __shfl_xor(rA[j], 16, 64);
            rA[j] += __shfl_xor(rA[j], 32, 64);
            rB[j] += __shfl_xor(rB[j], 16, 64);
            rB[j] += __shfl_xor(rB[j], 32, 64);
        }
        if (rowgrp == 0) {
            uint4 oA, oB;
            oA.x = (uint32_t)f2bf(rA[0]) | ((uint32_t)f2bf(rA[1]) << 16);
            oA.y = (uint32_t)f2bf(rA[2]) | ((uint32_t)f2bf(rA[3]) << 16);
            oA.z = (uint32_t)f2bf(rA[4]) | ((uint32_t)f2bf(rA[5]) << 16);
            oA.w = (uint32_t)f2bf(rA[6]) | ((uint32_t)f2bf(rA[7]) << 16);
            oB.x = (uint32_t)f2bf(rB[0]) | ((uint32_t)f2bf(rB[1]) << 16);
            oB.y = (uint32_t)f2bf(rB[2]) | ((uint32_t)f2bf(rB[3]) << 16);
            oB.z = (uint32_t)f2bf(rB[4]) | ((uint32_t)f2bf(rB[5]) << 16);
            oB.w = (uint32_t)f2bf(rB[6]) | ((uint32_t)f2bf(rB[7]) << 16);
            *(uint4*)(st + nl * 256 + ((c16 ^ (nl & 7)) << 4)) = oA;
            *(uint4*)(st + (nl + 1) * 256 + ((c16 ^ ((nl + 1) & 7)) << 4)) = oB;
        }
    }

    // ---- phase 2: 16x128 GEMM from LDS tile; B (pre-swizzled W) from global ----
    int q = rowgrp, l16 = c16;
    short8 afr[4];
    #pragma unroll
    for (int kb = 0; kb < 4; ++kb)
        afr[kb] = *(const short8*)(st + l16 * 256 + ((((kb << 2) + q) ^ (l16 & 7)) << 4));
    float scal[4];
    #pragma unroll
    for (int b = 0; b < 4; ++b) {
        int r = nodebase + q * 4 + b;
        scal[b] = (r < NNODE) ? (mode ? cia[r] * cja[r] : cia[r]) : 0.f;
    }
    #pragma unroll
    for (int cb = 0; cb < 8; ++cb) {
        int c = cb * 16 + l16;
        f32x4 acc = {0.f, 0.f, 0.f, 0.f};
        #pragma unroll
        for (int kb = 0; kb < 4; ++kb) {
            int byte = (c * 256 + 2 * (kb * 32 + q * 8)) ^ ((c & 7) << 4);
            short8 bHi = *(const short8*)((const char*)wsm + byte);
            short8 bLo = *(const short8*)((const char*)wsm + 32768 + byte);
            acc = __builtin_amdgcn_mfma_f32_16x16x32_bf16(afr[kb], bHi, acc, 0, 0, 0);
            acc = __builtin_amdgcn_mfma_f32_16x16x32_bf16(afr[kb], bLo, acc, 0, 0, 0);
        }
        #pragma unroll
        for (int b = 0; b < 4; ++b) {
            int r = nodebase + q * 4 + b;
            if (r < NNODE)
                outB[(size_t)r * KDIM + c] = f2bf(acc[b] * scal[b]);
        }
    }
}

// ---------------- output assembly (w1/w2 bf16 -> f32 out) ----------------
__global__ void out_k(const ushort* __restrict__ w1, const ushort* __restrict__ w2,
                      const float* __restrict__ disc, const float* __restrict__ kn,
                      const int* __restrict__ sid, const int* __restrict__ eid,
                      float* __restrict__ out) {
    const int total = 2 * BATCH * KDIM + BATCH + KDIM * KDIM;
    for (int i = blockIdx.x * blockDim.x + threadIdx.x; i < total;
         i += gridDim.x * blockDim.x) {
        if (i < BATCH * KDIM) {
            int b = i >> 7, c = i & 127;
            size_t n = (size_t)sid[b];
            out[i] = bf2f(w1[n * KDIM + c]) + bf2f(w2[n * KDIM + c]);
        } else if (i < 2 * BATCH * KDIM) {
            int j = i - BATCH * KDIM;
            int b = j >> 7, c = j & 127;
            size_t n = (size_t)(S_NUM + eid[b]);
            out[i] = bf2f(w1[n * KDIM + c]) + bf2f(w2[n * KDIM + c]);
        } else if (i < 2 * BATCH * KDIM + BATCH) {
            out[i] = disc[eid[i - 2 * BATCH * KDIM]];
        } else {
            out[i] = kn[i - (2 * BATCH * KDIM + BATCH)];
        }
    }
}

static inline size_t align_up(size_t x) { return (x + 255) & ~(size_t)255; }

extern "C" void kernel_launch(void* const* d_in, const int* in_sizes, int n_in,
                              void* d_out, int out_size, void* d_ws, size_t ws_size,
                              hipStream_t stream) {
    const float* stu  = (const float*)d_in[0];
    const float* exer = (const float*)d_in[1];
    const float* kn   = (const float*)d_in[2];
    const float* disc = (const float*)d_in[3];
    const float* rW   = (const float*)d_in[4];
    const float* wW   = (const float*)d_in[5];
    const float* rci  = (const float*)d_in[6];
    const float* rcj  = (const float*)d_in[7];
    const float* wci  = (const float*)d_in[8];
    const float* wcj  = (const float*)d_in[9];
    const int* redge   = (const int*)d_in[10];
    const int* wedge   = (const int*)d_in[11];
    const int* sid     = (const int*)d_in[12];
    const int* eid     = (const int*)d_in[13];
    float* out         = (float*)d_out;

    char* p = (char*)d_ws;
    const size_t fB16 = align_up((size_t)(NNODE + 1) * KDIM * 2);   // +sentinel row
    ushort* featb = (ushort*)p; p += fB16;  // shared bf16 features (layer-1 gather)
    ushort* fcR = (ushort*)p; p += fB16;    // L2 output / L3 gather
    ushort* fcW = (ushort*)p; p += fB16;
    ushort* pR  = (ushort*)p; p += fB16;    // L1 output / L2 gather / L3 output (w1)
    ushort* pW  = (ushort*)p; p += fB16;    // (w2); aliases buckets pre-L1
    ushort* ws  = (ushort*)p; p += align_up((size_t)6 * 32768 * 2);   // 384 KB
    int* gbcnt = (int*)p; p += align_up((size_t)256 * 4);
    int* rpb = (int*)p; p += align_up((size_t)2 * NNODE * 4);
    int* rpe = (int*)p; p += align_up((size_t)2 * NNODE * 4);
    int* csr = (int*)p; p += align_up((size_t)256 * RCAP * 4);
    float* cjpR = (float*)p; p += align_up((size_t)(NNODE + 1) * 4);
    float* cjpW = (float*)p; p += align_up((size_t)(NNODE + 1) * 4);
    // buckets alias pR (256 x 8448 x 4B = 8.65 MB < 17.92 MB); consumed by
    // build_k before cvt1/aggemm touch pR.
    uint32_t* bpk = (uint32_t*)pR;

    const int agBlocks = 2 * ((NNODE + 63) / 64);   // 2188
    const int NB = (NEDGE + CHUNK - 1) / CHUNK;

    // ---- shared prep ----
    prepW_k<<<(6 * 16384 + 255) / 256, 256, 0, stream>>>(rW, wW, ws, gbcnt);
    bucket_k<<<2 * NB, 256, 0, stream>>>(redge, wedge, gbcnt, bpk);
    build_k<<<256, 256, 0, stream>>>(bpk, gbcnt, rpb, rpe, csr);
    cvt1_k<<<2048, 256, 0, stream>>>(stu, exer, rcj, wcj, (uint4*)featb,
                                     (uint4*)fcR, (uint4*)fcW, (uint4*)pR, (uint4*)pW,
                                     cjpR, cjpW);

    // ---- 3 fused agg+GEMM layers, both graphs per dispatch ----
    aggemm_k<1><<<agBlocks, 256, 0, stream>>>((const uint4*)featb, (const uint4*)featb,
                                              cjpR, cjpW, rpb, rpe, csr,
                                              ws + 0 * 32768, ws + 3 * 32768,
                                              rci, rcj, wci, wcj, pR, pW, 1);
    aggemm_k<0><<<agBlocks, 256, 0, stream>>>((const uint4*)pR, (const uint4*)pW,
                                              nullptr, nullptr, rpb, rpe, csr,
                                              ws + 1 * 32768, ws + 4 * 32768,
                                              rci, rcj, wci, wcj, fcR, fcW, 1);
    aggemm_k<0><<<agBlocks, 256, 0, stream>>>((const uint4*)fcR, (const uint4*)fcW,
                                              nullptr, nullptr, rpb, rpe, csr,
                                              ws + 2 * 32768, ws + 5 * 32768,
                                              rci, rcj, wci, wcj, pR, pW, 0);

    out_k<<<2048, 256, 0, stream>>>(pR, pW, disc, kn, sid, eid, out);
}

// Round 11
// 405.189 us; speedup vs baseline: 1.0019x; 1.0019x over previous
//
#include <hip/hip_runtime.h>
#include <hip/hip_bf16.h>
#include <stdint.h>

#define S_NUM 50000
#define E_NUM 20000
#define NNODE 70000
#define KDIM 128
#define BATCH 8192
#define NEDGE 1000000

#define NRANGE 128            // dst-ranges per graph
#define RSZ 547               // ceil(NNODE / NRANGE)
#define BUCKET_CAP 8448       // per-bucket capacity (mean 7813, sigma 88)
#define RCAP 16672            // per-range padded csr region (>= 8448 + 547*15)
#define CHUNK 8192            // edges per bucket_k block
#define BINCAP 120            // LDS bin capacity
#define GR 256                // gemm rows per block
#define CAPC 16384            // max compacted L3 nodes (2*BATCH)

typedef __attribute__((ext_vector_type(8))) short short8;
typedef __attribute__((ext_vector_type(4))) float f32x4;
typedef __attribute__((ext_vector_type(2))) float f32x2;

__device__ __forceinline__ float bf2f(ushort u) {
    union { uint32_t i; float f; } v; v.i = ((uint32_t)u) << 16; return v.f;
}
__device__ __forceinline__ ushort f2bf(float f) {
    union { uint32_t i; float f; } v; v.f = f;
    uint32_t r = v.i + 0x7fffu + ((v.i >> 16) & 1u);
    return (ushort)(r >> 16);
}
// unpack 2 bf16 (packed in uint32) -> f32x2 {lo, hi}
__device__ __forceinline__ f32x2 up2(uint32_t u) {
    union { uint32_t i; float f; } lo, hi;
    lo.i = u << 16; hi.i = u & 0xffff0000u;
    f32x2 r; r.x = lo.f; r.y = hi.f; return r;
}

// ---------------- W prep (+ gbcnt/flags zero): bf16 hi/lo split, swizzled ----------------
__global__ void prepW_k(const float* __restrict__ rW, const float* __restrict__ wW,
                        ushort* __restrict__ ws, int* __restrict__ gbcnt,
                        int* __restrict__ flags) {
    int t = blockIdx.x * blockDim.x + threadIdx.x;
    if (blockIdx.x == 0 && threadIdx.x < 256) gbcnt[threadIdx.x] = 0;
    if (t < NNODE) flags[t] = 0;
    if (t >= 6 * 16384) return;
    int m = t >> 14, idx = t & 16383;
    const float* W = (m < 3) ? rW + m * 16384 : wW + (m - 3) * 16384;
    float x = W[idx];
    int k = idx >> 7, c = idx & 127;
    ushort hb = f2bf(x);
    ushort lb = f2bf(x - bf2f(hb));
    int off = ((c * 256 + 2 * k) ^ ((c & 7) << 4)) >> 1;
    ws[(size_t)m * 32768 + off] = hb;
    ws[(size_t)m * 32768 + 16384 + off] = lb;
}

// ---------------- pass 1: bin edges by dst-range, packed (local_dst<<17 | src) -------------
__global__ __launch_bounds__(256) void bucket_k(const int* __restrict__ redge,
                                                const int* __restrict__ wedge,
                                                int* __restrict__ gbcnt,
                                                uint32_t* __restrict__ bpk) {
    __shared__ uint32_t lpk[NRANGE][BINCAP];
    __shared__ int lcnt[NRANGE];
    __shared__ int gbase[NRANGE];
    const int NB = (NEDGE + CHUNK - 1) / CHUNK;
    int bid = blockIdx.x;
    int graph = bid >= NB;
    int cb = graph ? bid - NB : bid;
    const int* eg = graph ? wedge : redge;
    int e0 = cb * CHUNK;
    int nthis = min(CHUNK, NEDGE - e0);
    for (int i = threadIdx.x; i < NRANGE; i += 256) lcnt[i] = 0;
    __syncthreads();
    for (int i = threadIdx.x; i < nthis; i += 256) {
        int s = eg[e0 + i];
        int d = eg[NEDGE + e0 + i];
        int b = d / RSZ;
        uint32_t p = ((uint32_t)(d - b * RSZ) << 17) | (uint32_t)s;
        int slot = atomicAdd(&lcnt[b], 1);
        if (slot < BINCAP) lpk[b][slot] = p;
        else {
            int gs = atomicAdd(&gbcnt[graph * NRANGE + b], 1);
            if (gs < BUCKET_CAP)
                bpk[(size_t)(graph * NRANGE + b) * BUCKET_CAP + gs] = p;
        }
    }
    __syncthreads();
    for (int b = threadIdx.x; b < NRANGE; b += 256) {
        int c = min(lcnt[b], BINCAP);
        lcnt[b] = c;
        gbase[b] = atomicAdd(&gbcnt[graph * NRANGE + b], c);
    }
    __syncthreads();
    for (int b = 0; b < NRANGE; ++b) {
        int c = lcnt[b];
        size_t base = (size_t)(graph * NRANGE + b) * BUCKET_CAP + gbase[b];
        for (int i = threadIdx.x; i < c; i += 256)
            if (gbase[b] + i < BUCKET_CAP) bpk[base + i] = lpk[b][i];
    }
}

// ---------------- pass 2: CSR slice in LDS, 16-padded rows, fixed per-combo regions --------
__global__ __launch_bounds__(256) void build_k(const uint32_t* __restrict__ bpk,
                                               const int* __restrict__ gbcnt,
                                               int* __restrict__ rpb,
                                               int* __restrict__ rpe,
                                               int* __restrict__ csr) {
    __shared__ int lcnt[RSZ];
    __shared__ int lexcl[RSZ];
    __shared__ int pexcl[RSZ];
    __shared__ int lcur[RSZ];
    __shared__ int sliceB[BUCKET_CAP];
    __shared__ int wsum[4];
    __shared__ int s_carry;
    int combo = blockIdx.x;                 // 0..255
    int graph = combo >> 7, grp = combo & (NRANGE - 1);
    int lo = grp * RSZ;
    int rsize = min(RSZ, NNODE - lo);
    int n = min(gbcnt[combo], BUCKET_CAP);
    const uint32_t* bp = bpk + (size_t)combo * BUCKET_CAP;
    int* rpbg = rpb + graph * NNODE;
    int* rpeg = rpe + graph * NNODE;
    int* og = csr + (size_t)combo * RCAP;
    const int rbase = combo * RCAP;
    int tid = threadIdx.x, lane = tid & 63, wid = tid >> 6;

    for (int i = tid; i < rsize; i += 256) lcnt[i] = 0;
    if (tid == 0) s_carry = 0;
    __syncthreads();
    for (int i = tid; i < n; i += 256)
        atomicAdd(&lcnt[bp[i] >> 17], 1);
    __syncthreads();
    // scan 1: real counts -> lexcl
    for (int base = 0; base < rsize; base += 256) {
        int i = base + tid;
        int v = (i < rsize) ? lcnt[i] : 0;
        int incl = v;
        #pragma unroll
        for (int off = 1; off < 64; off <<= 1) {
            int t = __shfl_up(incl, off, 64);
            if (lane >= off) incl += t;
        }
        if (lane == 63) wsum[wid] = incl;
        __syncthreads();
        int carry = s_carry;
        if (wid == 0 && lane < 4) {
            int wv = wsum[lane];
            #pragma unroll
            for (int off = 1; off < 4; off <<= 1) {
                int t = __shfl_up(wv, off, 64);
                if (lane >= off) wv += t;
            }
            wsum[lane] = wv;
        }
        __syncthreads();
        int waveoff = (wid == 0) ? 0 : wsum[wid - 1];
        int excl = carry + waveoff + incl - v;
        if (i < rsize) { lexcl[i] = excl; lcur[i] = excl; }
        __syncthreads();
        if (tid == 0) s_carry = carry + wsum[3];
        __syncthreads();
    }
    if (tid == 0) s_carry = 0;
    __syncthreads();
    // scan 2: padded counts -> pexcl
    for (int base = 0; base < rsize; base += 256) {
        int i = base + tid;
        int v = (i < rsize) ? ((lcnt[i] + 15) & ~15) : 0;
        int incl = v;
        #pragma unroll
        for (int off = 1; off < 64; off <<= 1) {
            int t = __shfl_up(incl, off, 64);
            if (lane >= off) incl += t;
        }
        if (lane == 63) wsum[wid] = incl;
        __syncthreads();
        int carry = s_carry;
        if (wid == 0 && lane < 4) {
            int wv = wsum[lane];
            #pragma unroll
            for (int off = 1; off < 4; off <<= 1) {
                int t = __shfl_up(wv, off, 64);
                if (lane >= off) wv += t;
            }
            wsum[lane] = wv;
        }
        __syncthreads();
        int waveoff = (wid == 0) ? 0 : wsum[wid - 1];
        int excl = carry + waveoff + incl - v;
        if (i < rsize) pexcl[i] = excl;
        __syncthreads();
        if (tid == 0) s_carry = carry + wsum[3];
        __syncthreads();
    }
    for (int i = tid; i < rsize; i += 256) {
        int pc = (lcnt[i] + 15) & ~15;
        rpbg[lo + i] = rbase + pexcl[i];
        rpeg[lo + i] = rbase + pexcl[i] + pc;
    }
    for (int i = tid; i < n; i += 256) {
        uint32_t p = bp[i];
        int slot = atomicAdd(&lcur[p >> 17], 1);
        sliceB[slot] = (int)p;
    }
    __syncthreads();
    for (int i = tid; i < n; i += 256) {
        uint32_t p = (uint32_t)sliceB[i];
        int r = p >> 17;
        og[pexcl[r] + (i - lexcl[r])] = (int)(p & 0x1FFFFu);
    }
    for (int r = tid; r < rsize; r += 256) {
        int c = lcnt[r], pc = (c + 15) & ~15, b = pexcl[r];
        for (int j = c; j < pc; ++j) og[b + j] = NNODE;
    }
}

// ---------------- mark nodes needed by the output gather ----------------
__global__ void mark_k(const int* __restrict__ sid, const int* __restrict__ eid,
                       int* __restrict__ flags) {
    int i = blockIdx.x * blockDim.x + threadIdx.x;
    if (i < BATCH) flags[sid[i]] = 1;
    else if (i < 2 * BATCH) flags[S_NUM + eid[i - BATCH]] = 1;
}

// ---------------- compact flagged nodes -> list / inv / nsel (deterministic) ----------------
__global__ __launch_bounds__(1024) void compact_k(const int* __restrict__ flags,
                                                  int* __restrict__ list,
                                                  int* __restrict__ inv,
                                                  int* __restrict__ nsel) {
    __shared__ int wsum[16];
    __shared__ int s_carry;
    int tid = threadIdx.x, lane = tid & 63, wid = tid >> 6;
    if (tid == 0) s_carry = 0;
    __syncthreads();
    for (int base = 0; base < NNODE; base += 1024) {
        int i = base + tid;
        int v = (i < NNODE) ? flags[i] : 0;
        int incl = v;
        #pragma unroll
        for (int off = 1; off < 64; off <<= 1) {
            int t = __shfl_up(incl, off, 64);
            if (lane >= off) incl += t;
        }
        if (lane == 63) wsum[wid] = incl;
        __syncthreads();
        int carry = s_carry;
        if (wid == 0 && lane < 16) {
            int wv = wsum[lane];
            #pragma unroll
            for (int off = 1; off < 16; off <<= 1) {
                int t = __shfl_up(wv, off, 64);
                if (lane >= off) wv += t;
            }
            wsum[lane] = wv;
        }
        __syncthreads();
        int waveoff = (wid == 0) ? 0 : wsum[wid - 1];
        int excl = carry + waveoff + incl - v;
        if (i < NNODE && v) { list[excl] = i; inv[i] = excl; }
        __syncthreads();
        if (tid == 0) s_carry = carry + wsum[15];
        __syncthreads();
    }
    if (tid == 0) nsel[0] = s_carry;
}

// ---------------- cvt: featb = bf16([stu; exer]) + sentinel rows + padded cj copies --------
__global__ __launch_bounds__(256) void cvt1_k(const float* __restrict__ stu,
                                              const float* __restrict__ exer,
                                              const float* __restrict__ rcj,
                                              const float* __restrict__ wcj,
                                              uint4* __restrict__ featb,
                                              uint4* __restrict__ fcR,
                                              uint4* __restrict__ fcW,
                                              float* __restrict__ cjpR,
                                              float* __restrict__ cjpW) {
    const int main = NNODE * 16;           // uint4 per row
    const int total = main + 48 + 2 * (NNODE + 1);
    const uint4 z4 = {0, 0, 0, 0};
    for (int i = blockIdx.x * blockDim.x + threadIdx.x; i < total;
         i += gridDim.x * blockDim.x) {
        if (i < main) {
            int node = i >> 4;
            int qq = i & 15;
            const float4* src = (const float4*)((node < S_NUM)
                                  ? stu + (size_t)node * KDIM
                                  : exer + (size_t)(node - S_NUM) * KDIM);
            float4 a = src[qq * 2];
            float4 b = src[qq * 2 + 1];
            uint4 o;
            o.x = (uint32_t)f2bf(a.x) | ((uint32_t)f2bf(a.y) << 16);
            o.y = (uint32_t)f2bf(a.z) | ((uint32_t)f2bf(a.w) << 16);
            o.z = (uint32_t)f2bf(b.x) | ((uint32_t)f2bf(b.y) << 16);
            o.w = (uint32_t)f2bf(b.z) | ((uint32_t)f2bf(b.w) << 16);
            featb[i] = o;
        } else if (i < main + 48) {
            int j = i - main;
            size_t off = (size_t)NNODE * 16 + (j & 15);
            switch (j >> 4) {
                case 0: featb[off] = z4; break;
                case 1: fcR[off] = z4; break;
                default: fcW[off] = z4; break;
            }
        } else {
            int k = i - main - 48;
            if (k <= NNODE)  cjpR[k] = (k < NNODE) ? rcj[k] : 0.f;
            else {
                int m = k - (NNODE + 1);
                cjpW[m] = (m < NNODE) ? wcj[m] : 0.f;
            }
        }
    }
}

// ---------------- aggregation, both graphs: 16-lane group = one node ----------------
// lane&15 owns 8 dims (uint4); no cross-lane reduction. 8 edges unrolled ->
// 16 loads in flight per lane. COMPACT: node list from L3 sparsification.
template<int USECJ, int COMPACT>
__global__ __launch_bounds__(256) void agg2_k(const uint4* __restrict__ srcR,
                                              const uint4* __restrict__ srcW,
                                              const float* __restrict__ cjR,
                                              const float* __restrict__ cjW,
                                              const int* __restrict__ rpb,
                                              const int* __restrict__ rpe,
                                              const int* __restrict__ csr,
                                              const int* __restrict__ list,
                                              const int* __restrict__ nselp,
                                              uint4* __restrict__ outR,
                                              uint4* __restrict__ outW) {
    int lane = threadIdx.x & 63, wid = threadIdx.x >> 6;
    int grp = lane >> 4, c16 = lane & 15;
    int gi = blockIdx.x * 16 + wid * 4 + grp;
    int graph, n, orow;
    if (COMPACT) {
        int nsel = nselp[0];
        graph = gi >= CAPC;
        int ci = graph ? gi - CAPC : gi;
        if (ci >= nsel) return;
        n = list[ci];
        orow = ci;
    } else {
        if (gi >= 2 * NNODE) return;
        graph = gi >= NNODE;
        n = graph ? gi - NNODE : gi;
        orow = n;
    }
    const uint4* fc = graph ? srcW : srcR;
    const float* cjg = graph ? cjW : cjR;
    int beg = (rpb + graph * NNODE)[n];
    int end = (rpe + graph * NNODE)[n];
    uint4* outp = graph ? outW : outR;

    f32x2 a0 = {0.f, 0.f}, a1 = {0.f, 0.f}, a2 = {0.f, 0.f}, a3 = {0.f, 0.f};
    for (int e = beg; e < end; e += 8) {
        int s0 = csr[e],     s1 = csr[e + 1], s2 = csr[e + 2], s3 = csr[e + 3];
        int s4 = csr[e + 4], s5 = csr[e + 5], s6 = csr[e + 6], s7 = csr[e + 7];
        uint4 u0 = fc[(size_t)s0 * 16 + c16];
        uint4 u1 = fc[(size_t)s1 * 16 + c16];
        uint4 u2 = fc[(size_t)s2 * 16 + c16];
        uint4 u3 = fc[(size_t)s3 * 16 + c16];
        uint4 u4 = fc[(size_t)s4 * 16 + c16];
        uint4 u5 = fc[(size_t)s5 * 16 + c16];
        uint4 u6 = fc[(size_t)s6 * 16 + c16];
        uint4 u7 = fc[(size_t)s7 * 16 + c16];
        if (USECJ) {
            float c0 = cjg[s0], c1 = cjg[s1], c2 = cjg[s2], c3 = cjg[s3];
            float c4 = cjg[s4], c5 = cjg[s5], c6 = cjg[s6], c7 = cjg[s7];
            f32x2 v0 = {c0, c0}, v1 = {c1, c1}, v2 = {c2, c2}, v3 = {c3, c3};
            f32x2 v4 = {c4, c4}, v5 = {c5, c5}, v6 = {c6, c6}, v7 = {c7, c7};
            a0 += v0 * up2(u0.x) + v1 * up2(u1.x) + v2 * up2(u2.x) + v3 * up2(u3.x)
                + v4 * up2(u4.x) + v5 * up2(u5.x) + v6 * up2(u6.x) + v7 * up2(u7.x);
            a1 += v0 * up2(u0.y) + v1 * up2(u1.y) + v2 * up2(u2.y) + v3 * up2(u3.y)
                + v4 * up2(u4.y) + v5 * up2(u5.y) + v6 * up2(u6.y) + v7 * up2(u7.y);
            a2 += v0 * up2(u0.z) + v1 * up2(u1.z) + v2 * up2(u2.z) + v3 * up2(u3.z)
                + v4 * up2(u4.z) + v5 * up2(u5.z) + v6 * up2(u6.z) + v7 * up2(u7.z);
            a3 += v0 * up2(u0.w) + v1 * up2(u1.w) + v2 * up2(u2.w) + v3 * up2(u3.w)
                + v4 * up2(u4.w) + v5 * up2(u5.w) + v6 * up2(u6.w) + v7 * up2(u7.w);
        } else {
            a0 += (up2(u0.x) + up2(u1.x)) + (up2(u2.x) + up2(u3.x))
                + (up2(u4.x) + up2(u5.x)) + (up2(u6.x) + up2(u7.x));
            a1 += (up2(u0.y) + up2(u1.y)) + (up2(u2.y) + up2(u3.y))
                + (up2(u4.y) + up2(u5.y)) + (up2(u6.y) + up2(u7.y));
            a2 += (up2(u0.z) + up2(u1.z)) + (up2(u2.z) + up2(u3.z))
                + (up2(u4.z) + up2(u5.z)) + (up2(u6.z) + up2(u7.z));
            a3 += (up2(u0.w) + up2(u1.w)) + (up2(u2.w) + up2(u3.w))
                + (up2(u4.w) + up2(u5.w)) + (up2(u6.w) + up2(u7.w));
        }
    }
    uint4 o;
    o.x = (uint32_t)f2bf(a0.x) | ((uint32_t)f2bf(a0.y) << 16);
    o.y = (uint32_t)f2bf(a1.x) | ((uint32_t)f2bf(a1.y) << 16);
    o.z = (uint32_t)f2bf(a2.x) | ((uint32_t)f2bf(a2.y) << 16);
    o.w = (uint32_t)f2bf(a3.x) | ((uint32_t)f2bf(a3.y) << 16);
    outp[(size_t)orow * 16 + c16] = o;
}

// ---------------- fused GEMM, both graphs, 256 rows/block; COMPACT for L3 ----------------
template<int COMPACT>
__global__ __launch_bounds__(256) void gemm2_k(const ushort* __restrict__ AR,
                                               const ushort* __restrict__ AW,
                                               const ushort* __restrict__ wsR,
                                               const ushort* __restrict__ wsW,
                                               const float* __restrict__ rci,
                                               const float* __restrict__ rcj,
                                               const float* __restrict__ wci,
                                               const float* __restrict__ wcj,
                                               const int* __restrict__ list,
                                               const int* __restrict__ nselp,
                                               ushort* __restrict__ outR,
                                               ushort* __restrict__ outW,
                                               int mode) {
    const int halfBlocks = COMPACT ? (CAPC / GR) : ((NNODE + GR - 1) / GR);
    int graph = blockIdx.x >= halfBlocks;
    int bb = graph ? blockIdx.x - halfBlocks : blockIdx.x;
    int nrows = COMPACT ? nselp[0] : NNODE;
    const ushort* A = graph ? AW : AR;
    const ushort* wsm = graph ? wsW : wsR;
    const float* ci = graph ? wci : rci;
    const float* cj = graph ? wcj : rcj;
    ushort* outB = graph ? outW : outR;

    __shared__ ushort wt[32768];   // 64 KB: hi + lo plane, pre-swizzled
    {
        const uint4* g = (const uint4*)wsm;
        uint4* l = (uint4*)wt;
        for (int i = threadIdx.x; i < 4096; i += 256) l[i] = g[i];
    }
    __syncthreads();

    int wid = threadIdx.x >> 6, lane = threadIdx.x & 63;
    int q = lane >> 4, l16 = lane & 15;
    int rbase = bb * GR + wid * 64;
    if (rbase >= nrows) return;

    short8 z8 = {0, 0, 0, 0, 0, 0, 0, 0};
    short8 afr[4][4];
    #pragma unroll
    for (int t = 0; t < 4; ++t) {
        int row = rbase + t * 16 + l16;
        bool rok = row < nrows;
        const short8* ar = (const short8*)(A + (size_t)row * KDIM);
        #pragma unroll
        for (int kb = 0; kb < 4; ++kb)
            afr[t][kb] = rok ? ar[kb * 4 + q] : z8;
    }
    float scal[4][4];
    #pragma unroll
    for (int t = 0; t < 4; ++t)
        #pragma unroll
        for (int b = 0; b < 4; ++b) {
            int r = rbase + t * 16 + q * 4 + b;
            bool ok = r < nrows;
            int node = COMPACT ? (ok ? list[r] : 0) : r;
            scal[t][b] = ok ? (mode ? ci[node] * cj[node] : ci[node]) : 0.f;
        }

    #pragma unroll
    for (int cb = 0; cb < 8; ++cb) {
        int c = cb * 16 + l16;
        short8 bHi[4], bLo[4];
        #pragma unroll
        for (int kb = 0; kb < 4; ++kb) {
            int byte = (c * 256 + 2 * (kb * 32 + q * 8)) ^ ((c & 7) << 4);
            bHi[kb] = *(const short8*)((const char*)wt + byte);
            bLo[kb] = *(const short8*)((const char*)wt + 32768 + byte);
        }
        #pragma unroll
        for (int t = 0; t < 4; ++t) {
            f32x4 acc = {0.f, 0.f, 0.f, 0.f};
            #pragma unroll
            for (int kb = 0; kb < 4; ++kb) {
                acc = __builtin_amdgcn_mfma_f32_16x16x32_bf16(afr[t][kb], bHi[kb], acc, 0, 0, 0);
                acc = __builtin_amdgcn_mfma_f32_16x16x32_bf16(afr[t][kb], bLo[kb], acc, 0, 0, 0);
            }
            #pragma unroll
            for (int b = 0; b < 4; ++b) {
                int r = rbase + t * 16 + q * 4 + b;
                if (r < nrows)
                    outB[(size_t)r * KDIM + c] = f2bf(acc[b] * scal[t][b]);
            }
        }
    }
}

// ---------------- output assembly (compacted w1c/w2c bf16 -> f32 out) ----------------
__global__ void out_k(const ushort* __restrict__ w1c, const ushort* __restrict__ w2c,
                      const int* __restrict__ inv,
                      const float* __restrict__ disc, const float* __restrict__ kn,
                      const int* __restrict__ sid, const int* __restrict__ eid,
                      float* __restrict__ out) {
    const int total = 2 * BATCH * KDIM + BATCH + KDIM * KDIM;
    for (int i = blockIdx.x * blockDim.x + threadIdx.x; i < total;
         i += gridDim.x * blockDim.x) {
        if (i < BATCH * KDIM) {
            int b = i >> 7, c = i & 127;
            size_t r = (size_t)inv[sid[b]];
            out[i] = bf2f(w1c[r * KDIM + c]) + bf2f(w2c[r * KDIM + c]);
        } else if (i < 2 * BATCH * KDIM) {
            int j = i - BATCH * KDIM;
            int b = j >> 7, c = j & 127;
            size_t r = (size_t)inv[S_NUM + eid[b]];
            out[i] = bf2f(w1c[r * KDIM + c]) + bf2f(w2c[r * KDIM + c]);
        } else if (i < 2 * BATCH * KDIM + BATCH) {
            out[i] = disc[eid[i - 2 * BATCH * KDIM]];
        } else {
            out[i] = kn[i - (2 * BATCH * KDIM + BATCH)];
        }
    }
}

static inline size_t align_up(size_t x) { return (x + 255) & ~(size_t)255; }

extern "C" void kernel_launch(void* const* d_in, const int* in_sizes, int n_in,
                              void* d_out, int out_size, void* d_ws, size_t ws_size,
                              hipStream_t stream) {
    const float* stu  = (const float*)d_in[0];
    const float* exer = (const float*)d_in[1];
    const float* kn   = (const float*)d_in[2];
    const float* disc = (const float*)d_in[3];
    const float* rW   = (const float*)d_in[4];
    const float* wW   = (const float*)d_in[5];
    const float* rci  = (const float*)d_in[6];
    const float* rcj  = (const float*)d_in[7];
    const float* wci  = (const float*)d_in[8];
    const float* wcj  = (const float*)d_in[9];
    const int* redge   = (const int*)d_in[10];
    const int* wedge   = (const int*)d_in[11];
    const int* sid     = (const int*)d_in[12];
    const int* eid     = (const int*)d_in[13];
    float* out         = (float*)d_out;

    char* p = (char*)d_ws;
    const size_t fB16 = align_up((size_t)(NNODE + 1) * KDIM * 2);   // +sentinel row
    ushort* featb = (ushort*)p; p += fB16;  // L1 gather src; later w1c/w2c (compact, 8MB)
    ushort* fcR = (ushort*)p; p += fB16;
    ushort* fcW = (ushort*)p; p += fB16;
    ushort* pR  = (ushort*)p; p += fB16;    // agg out; aliases buckets pre-L1
    ushort* pW  = (ushort*)p; p += fB16;
    ushort* ws  = (ushort*)p; p += align_up((size_t)6 * 32768 * 2);   // 384 KB
    int* gbcnt = (int*)p; p += align_up((size_t)256 * 4);
    int* rpb = (int*)p; p += align_up((size_t)2 * NNODE * 4);
    int* rpe = (int*)p; p += align_up((size_t)2 * NNODE * 4);
    int* csr = (int*)p; p += align_up((size_t)256 * RCAP * 4);
    float* cjpR = (float*)p; p += align_up((size_t)(NNODE + 1) * 4);
    float* cjpW = (float*)p; p += align_up((size_t)(NNODE + 1) * 4);
    int* flags = (int*)p; p += align_up((size_t)NNODE * 4);
    int* list  = (int*)p; p += align_up((size_t)CAPC * 4);
    int* inv   = (int*)p; p += align_up((size_t)NNODE * 4);
    int* nsel  = (int*)p; p += align_up((size_t)16 * 4);
    // buckets alias pR (256 x 8448 x 4B = 8.65 MB < 17.92 MB)
    uint32_t* bpk = (uint32_t*)pR;
    // compact outputs alias featb (2 x 16384 x 128 x 2B = 8 MB < 17.92 MB)
    ushort* w1c = featb;
    ushort* w2c = featb + (size_t)CAPC * KDIM;

    const int aggFull = (2 * NNODE + 15) / 16;      // 8750
    const int aggComp = 2 * CAPC / 16;              // 2048
    const int gemmFull = 2 * ((NNODE + GR - 1) / GR);
    const int gemmComp = 2 * (CAPC / GR);
    const int NB = (NEDGE + CHUNK - 1) / CHUNK;

    // ---- shared prep ----
    prepW_k<<<(6 * 16384 + 255) / 256, 256, 0, stream>>>(rW, wW, ws, gbcnt, flags);
    bucket_k<<<2 * NB, 256, 0, stream>>>(redge, wedge, gbcnt, bpk);
    build_k<<<256, 256, 0, stream>>>(bpk, gbcnt, rpb, rpe, csr);
    mark_k<<<(2 * BATCH + 255) / 256, 256, 0, stream>>>(sid, eid, flags);
    compact_k<<<1, 1024, 0, stream>>>(flags, list, inv, nsel);
    cvt1_k<<<2048, 256, 0, stream>>>(stu, exer, rcj, wcj, (uint4*)featb,
                                     (uint4*)fcR, (uint4*)fcW, cjpR, cjpW);

    // ---- L1 (full) ----
    agg2_k<1, 0><<<aggFull, 256, 0, stream>>>((const uint4*)featb, (const uint4*)featb,
                                              cjpR, cjpW, rpb, rpe, csr, nullptr, nullptr,
                                              (uint4*)pR, (uint4*)pW);
    gemm2_k<0><<<gemmFull, 256, 0, stream>>>(pR, pW, ws + 0 * 32768, ws + 3 * 32768,
                                             rci, rcj, wci, wcj, nullptr, nullptr,
                                             fcR, fcW, 1);
    // ---- L2 (full) ----
    agg2_k<0, 0><<<aggFull, 256, 0, stream>>>((const uint4*)fcR, (const uint4*)fcW,
                                              nullptr, nullptr, rpb, rpe, csr,
                                              nullptr, nullptr, (uint4*)pR, (uint4*)pW);
    gemm2_k<0><<<gemmFull, 256, 0, stream>>>(pR, pW, ws + 1 * 32768, ws + 4 * 32768,
                                             rci, rcj, wci, wcj, nullptr, nullptr,
                                             fcR, fcW, 1);
    // ---- L3 (compact: only nodes the output reads) ----
    agg2_k<0, 1><<<aggComp, 256, 0, stream>>>((const uint4*)fcR, (const uint4*)fcW,
                                              nullptr, nullptr, rpb, rpe, csr,
                                              list, nsel, (uint4*)pR, (uint4*)pW);
    gemm2_k<1><<<gemmComp, 256, 0, stream>>>(pR, pW, ws + 2 * 32768, ws + 5 * 32768,
                                             rci, rcj, wci, wcj, list, nsel,
                                             w1c, w2c, 0);

    out_k<<<2048, 256, 0, stream>>>(w1c, w2c, inv, disc, kn, sid, eid, out);
}

// Round 12
// 349.748 us; speedup vs baseline: 1.1607x; 1.1585x over previous
//
#include <hip/hip_runtime.h>
#include <hip/hip_bf16.h>
#include <stdint.h>

#define S_NUM 50000
#define E_NUM 20000
#define NNODE 70000
#define KDIM 128
#define BATCH 8192
#define NEDGE 1000000

#define NRANGE 128            // dst-ranges per graph
#define RSZ 547               // ceil(NNODE / NRANGE)
#define BUCKET_CAP 8448       // per-bucket capacity (mean 7813, sigma 88)
#define RCAP 16672            // per-range padded csr region (>= 8448 + 547*15)
#define CHUNK 8192            // edges per bucket_k block
#define BINCAP 120            // LDS bin capacity
#define GR 256                // gemm rows per block
#define CAPC 16384            // max compacted L3 nodes (2*BATCH)

typedef __attribute__((ext_vector_type(8))) short short8;
typedef __attribute__((ext_vector_type(4))) float f32x4;
typedef __attribute__((ext_vector_type(2))) float f32x2;

__device__ __forceinline__ float bf2f(ushort u) {
    union { uint32_t i; float f; } v; v.i = ((uint32_t)u) << 16; return v.f;
}
__device__ __forceinline__ ushort f2bf(float f) {
    union { uint32_t i; float f; } v; v.f = f;
    uint32_t r = v.i + 0x7fffu + ((v.i >> 16) & 1u);
    return (ushort)(r >> 16);
}
// unpack 2 bf16 (packed in uint32) -> f32x2 {lo, hi}
__device__ __forceinline__ f32x2 up2(uint32_t u) {
    union { uint32_t i; float f; } lo, hi;
    lo.i = u << 16; hi.i = u & 0xffff0000u;
    f32x2 r; r.x = lo.f; r.y = hi.f; return r;
}

// ---------------- W prep (+ gbcnt/flags/nsel zero): bf16 hi/lo split, swizzled ------------
__global__ void prepW_k(const float* __restrict__ rW, const float* __restrict__ wW,
                        ushort* __restrict__ ws, int* __restrict__ gbcnt,
                        int* __restrict__ flags, int* __restrict__ nsel) {
    int t = blockIdx.x * blockDim.x + threadIdx.x;
    if (blockIdx.x == 0 && threadIdx.x < 256) gbcnt[threadIdx.x] = 0;
    if (t == 0) nsel[0] = 0;
    if (t < NNODE) flags[t] = 0;
    if (t >= 6 * 16384) return;
    int m = t >> 14, idx = t & 16383;
    const float* W = (m < 3) ? rW + m * 16384 : wW + (m - 3) * 16384;
    float x = W[idx];
    int k = idx >> 7, c = idx & 127;
    ushort hb = f2bf(x);
    ushort lb = f2bf(x - bf2f(hb));
    int off = ((c * 256 + 2 * k) ^ ((c & 7) << 4)) >> 1;
    ws[(size_t)m * 32768 + off] = hb;
    ws[(size_t)m * 32768 + 16384 + off] = lb;
}

// ---------------- pass 1: bin edges by dst-range, packed (local_dst<<17 | src) -------------
__global__ __launch_bounds__(256) void bucket_k(const int* __restrict__ redge,
                                                const int* __restrict__ wedge,
                                                int* __restrict__ gbcnt,
                                                uint32_t* __restrict__ bpk) {
    __shared__ uint32_t lpk[NRANGE][BINCAP];
    __shared__ int lcnt[NRANGE];
    __shared__ int gbase[NRANGE];
    const int NB = (NEDGE + CHUNK - 1) / CHUNK;
    int bid = blockIdx.x;
    int graph = bid >= NB;
    int cb = graph ? bid - NB : bid;
    const int* eg = graph ? wedge : redge;
    int e0 = cb * CHUNK;
    int nthis = min(CHUNK, NEDGE - e0);
    for (int i = threadIdx.x; i < NRANGE; i += 256) lcnt[i] = 0;
    __syncthreads();
    for (int i = threadIdx.x; i < nthis; i += 256) {
        int s = eg[e0 + i];
        int d = eg[NEDGE + e0 + i];
        int b = d / RSZ;
        uint32_t p = ((uint32_t)(d - b * RSZ) << 17) | (uint32_t)s;
        int slot = atomicAdd(&lcnt[b], 1);
        if (slot < BINCAP) lpk[b][slot] = p;
        else {
            int gs = atomicAdd(&gbcnt[graph * NRANGE + b], 1);
            if (gs < BUCKET_CAP)
                bpk[(size_t)(graph * NRANGE + b) * BUCKET_CAP + gs] = p;
        }
    }
    __syncthreads();
    for (int b = threadIdx.x; b < NRANGE; b += 256) {
        int c = min(lcnt[b], BINCAP);
        lcnt[b] = c;
        gbase[b] = atomicAdd(&gbcnt[graph * NRANGE + b], c);
    }
    __syncthreads();
    for (int b = 0; b < NRANGE; ++b) {
        int c = lcnt[b];
        size_t base = (size_t)(graph * NRANGE + b) * BUCKET_CAP + gbase[b];
        for (int i = threadIdx.x; i < c; i += 256)
            if (gbase[b] + i < BUCKET_CAP) bpk[base + i] = lpk[b][i];
    }
}

// ---------------- pass 2: CSR slice in LDS, 16-padded rows, fixed per-combo regions --------
__global__ __launch_bounds__(256) void build_k(const uint32_t* __restrict__ bpk,
                                               const int* __restrict__ gbcnt,
                                               int* __restrict__ rpb,
                                               int* __restrict__ rpe,
                                               int* __restrict__ csr) {
    __shared__ int lcnt[RSZ];
    __shared__ int lexcl[RSZ];
    __shared__ int pexcl[RSZ];
    __shared__ int lcur[RSZ];
    __shared__ int sliceB[BUCKET_CAP];
    __shared__ int wsum[4];
    __shared__ int s_carry;
    int combo = blockIdx.x;                 // 0..255
    int graph = combo >> 7, grp = combo & (NRANGE - 1);
    int lo = grp * RSZ;
    int rsize = min(RSZ, NNODE - lo);
    int n = min(gbcnt[combo], BUCKET_CAP);
    const uint32_t* bp = bpk + (size_t)combo * BUCKET_CAP;
    int* rpbg = rpb + graph * NNODE;
    int* rpeg = rpe + graph * NNODE;
    int* og = csr + (size_t)combo * RCAP;
    const int rbase = combo * RCAP;
    int tid = threadIdx.x, lane = tid & 63, wid = tid >> 6;

    for (int i = tid; i < rsize; i += 256) lcnt[i] = 0;
    if (tid == 0) s_carry = 0;
    __syncthreads();
    for (int i = tid; i < n; i += 256)
        atomicAdd(&lcnt[bp[i] >> 17], 1);
    __syncthreads();
    // scan 1: real counts -> lexcl
    for (int base = 0; base < rsize; base += 256) {
        int i = base + tid;
        int v = (i < rsize) ? lcnt[i] : 0;
        int incl = v;
        #pragma unroll
        for (int off = 1; off < 64; off <<= 1) {
            int t = __shfl_up(incl, off, 64);
            if (lane >= off) incl += t;
        }
        if (lane == 63) wsum[wid] = incl;
        __syncthreads();
        int carry = s_carry;
        if (wid == 0 && lane < 4) {
            int wv = wsum[lane];
            #pragma unroll
            for (int off = 1; off < 4; off <<= 1) {
                int t = __shfl_up(wv, off, 64);
                if (lane >= off) wv += t;
            }
            wsum[lane] = wv;
        }
        __syncthreads();
        int waveoff = (wid == 0) ? 0 : wsum[wid - 1];
        int excl = carry + waveoff + incl - v;
        if (i < rsize) { lexcl[i] = excl; lcur[i] = excl; }
        __syncthreads();
        if (tid == 0) s_carry = carry + wsum[3];
        __syncthreads();
    }
    if (tid == 0) s_carry = 0;
    __syncthreads();
    // scan 2: padded counts -> pexcl
    for (int base = 0; base < rsize; base += 256) {
        int i = base + tid;
        int v = (i < rsize) ? ((lcnt[i] + 15) & ~15) : 0;
        int incl = v;
        #pragma unroll
        for (int off = 1; off < 64; off <<= 1) {
            int t = __shfl_up(incl, off, 64);
            if (lane >= off) incl += t;
        }
        if (lane == 63) wsum[wid] = incl;
        __syncthreads();
        int carry = s_carry;
        if (wid == 0 && lane < 4) {
            int wv = wsum[lane];
            #pragma unroll
            for (int off = 1; off < 4; off <<= 1) {
                int t = __shfl_up(wv, off, 64);
                if (lane >= off) wv += t;
            }
            wsum[lane] = wv;
        }
        __syncthreads();
        int waveoff = (wid == 0) ? 0 : wsum[wid - 1];
        int excl = carry + waveoff + incl - v;
        if (i < rsize) pexcl[i] = excl;
        __syncthreads();
        if (tid == 0) s_carry = carry + wsum[3];
        __syncthreads();
    }
    for (int i = tid; i < rsize; i += 256) {
        int pc = (lcnt[i] + 15) & ~15;
        rpbg[lo + i] = rbase + pexcl[i];
        rpeg[lo + i] = rbase + pexcl[i] + pc;
    }
    for (int i = tid; i < n; i += 256) {
        uint32_t p = bp[i];
        int slot = atomicAdd(&lcur[p >> 17], 1);
        sliceB[slot] = (int)p;
    }
    __syncthreads();
    for (int i = tid; i < n; i += 256) {
        uint32_t p = (uint32_t)sliceB[i];
        int r = p >> 17;
        og[pexcl[r] + (i - lexcl[r])] = (int)(p & 0x1FFFFu);
    }
    for (int r = tid; r < rsize; r += 256) {
        int c = lcnt[r], pc = (c + 15) & ~15, b = pexcl[r];
        for (int j = c; j < pc; ++j) og[b + j] = NNODE;
    }
}

// ---------------- mark nodes needed by the output gather ----------------
__global__ void mark_k(const int* __restrict__ sid, const int* __restrict__ eid,
                       int* __restrict__ flags) {
    int i = blockIdx.x * blockDim.x + threadIdx.x;
    if (i < BATCH) flags[sid[i]] = 1;
    else if (i < 2 * BATCH) flags[S_NUM + eid[i - BATCH]] = 1;
}

// ---------------- order-free compaction (atomic; output invariant to row order) -----------
__global__ void compact_k(const int* __restrict__ flags, int* __restrict__ list,
                          int* __restrict__ inv, int* __restrict__ nsel) {
    for (int i = blockIdx.x * blockDim.x + threadIdx.x; i < NNODE;
         i += gridDim.x * blockDim.x) {
        if (flags[i]) {
            int pos = atomicAdd(nsel, 1);
            list[pos] = i;
            inv[i] = pos;
        }
    }
}

// ---------------- cvt: featb = bf16([stu; exer]) + sentinel rows + padded cj copies --------
__global__ __launch_bounds__(256) void cvt1_k(const float* __restrict__ stu,
                                              const float* __restrict__ exer,
                                              const float* __restrict__ rcj,
                                              const float* __restrict__ wcj,
                                              uint4* __restrict__ featb,
                                              uint4* __restrict__ fcR,
                                              uint4* __restrict__ fcW,
                                              float* __restrict__ cjpR,
                                              float* __restrict__ cjpW) {
    const int main = NNODE * 16;           // uint4 per row
    const int total = main + 48 + 2 * (NNODE + 1);
    const uint4 z4 = {0, 0, 0, 0};
    for (int i = blockIdx.x * blockDim.x + threadIdx.x; i < total;
         i += gridDim.x * blockDim.x) {
        if (i < main) {
            int node = i >> 4;
            int qq = i & 15;
            const float4* src = (const float4*)((node < S_NUM)
                                  ? stu + (size_t)node * KDIM
                                  : exer + (size_t)(node - S_NUM) * KDIM);
            float4 a = src[qq * 2];
            float4 b = src[qq * 2 + 1];
            uint4 o;
            o.x = (uint32_t)f2bf(a.x) | ((uint32_t)f2bf(a.y) << 16);
            o.y = (uint32_t)f2bf(a.z) | ((uint32_t)f2bf(a.w) << 16);
            o.z = (uint32_t)f2bf(b.x) | ((uint32_t)f2bf(b.y) << 16);
            o.w = (uint32_t)f2bf(b.z) | ((uint32_t)f2bf(b.w) << 16);
            featb[i] = o;
        } else if (i < main + 48) {
            int j = i - main;
            size_t off = (size_t)NNODE * 16 + (j & 15);
            switch (j >> 4) {
                case 0: featb[off] = z4; break;
                case 1: fcR[off] = z4; break;
                default: fcW[off] = z4; break;
            }
        } else {
            int k = i - main - 48;
            if (k <= NNODE)  cjpR[k] = (k < NNODE) ? rcj[k] : 0.f;
            else {
                int m = k - (NNODE + 1);
                cjpW[m] = (m < NNODE) ? wcj[m] : 0.f;
            }
        }
    }
}

// ---------------- aggregation, both graphs: 16-lane group = one node ----------------
// lane&15 owns 8 dims (uint4); no cross-lane reduction. 8 edges unrolled ->
// 16 loads in flight per lane. COMPACT: node list from L3 sparsification.
template<int USECJ, int COMPACT>
__global__ __launch_bounds__(256) void agg2_k(const uint4* __restrict__ srcR,
                                              const uint4* __restrict__ srcW,
                                              const float* __restrict__ cjR,
                                              const float* __restrict__ cjW,
                                              const int* __restrict__ rpb,
                                              const int* __restrict__ rpe,
                                              const int* __restrict__ csr,
                                              const int* __restrict__ list,
                                              const int* __restrict__ nselp,
                                              uint4* __restrict__ outR,
                                              uint4* __restrict__ outW) {
    int lane = threadIdx.x & 63, wid = threadIdx.x >> 6;
    int grp = lane >> 4, c16 = lane & 15;
    int gi = blockIdx.x * 16 + wid * 4 + grp;
    int graph, n, orow;
    if (COMPACT) {
        int nsel = nselp[0];
        graph = gi >= CAPC;
        int ci = graph ? gi - CAPC : gi;
        if (ci >= nsel) return;
        n = list[ci];
        orow = ci;
    } else {
        if (gi >= 2 * NNODE) return;
        graph = gi >= NNODE;
        n = graph ? gi - NNODE : gi;
        orow = n;
    }
    const uint4* fc = graph ? srcW : srcR;
    const float* cjg = graph ? cjW : cjR;
    int beg = (rpb + graph * NNODE)[n];
    int end = (rpe + graph * NNODE)[n];
    uint4* outp = graph ? outW : outR;

    f32x2 a0 = {0.f, 0.f}, a1 = {0.f, 0.f}, a2 = {0.f, 0.f}, a3 = {0.f, 0.f};
    for (int e = beg; e < end; e += 8) {
        int s0 = csr[e],     s1 = csr[e + 1], s2 = csr[e + 2], s3 = csr[e + 3];
        int s4 = csr[e + 4], s5 = csr[e + 5], s6 = csr[e + 6], s7 = csr[e + 7];
        uint4 u0 = fc[(size_t)s0 * 16 + c16];
        uint4 u1 = fc[(size_t)s1 * 16 + c16];
        uint4 u2 = fc[(size_t)s2 * 16 + c16];
        uint4 u3 = fc[(size_t)s3 * 16 + c16];
        uint4 u4 = fc[(size_t)s4 * 16 + c16];
        uint4 u5 = fc[(size_t)s5 * 16 + c16];
        uint4 u6 = fc[(size_t)s6 * 16 + c16];
        uint4 u7 = fc[(size_t)s7 * 16 + c16];
        if (USECJ) {
            float c0 = cjg[s0], c1 = cjg[s1], c2 = cjg[s2], c3 = cjg[s3];
            float c4 = cjg[s4], c5 = cjg[s5], c6 = cjg[s6], c7 = cjg[s7];
            f32x2 v0 = {c0, c0}, v1 = {c1, c1}, v2 = {c2, c2}, v3 = {c3, c3};
            f32x2 v4 = {c4, c4}, v5 = {c5, c5}, v6 = {c6, c6}, v7 = {c7, c7};
            a0 += v0 * up2(u0.x) + v1 * up2(u1.x) + v2 * up2(u2.x) + v3 * up2(u3.x)
                + v4 * up2(u4.x) + v5 * up2(u5.x) + v6 * up2(u6.x) + v7 * up2(u7.x);
            a1 += v0 * up2(u0.y) + v1 * up2(u1.y) + v2 * up2(u2.y) + v3 * up2(u3.y)
                + v4 * up2(u4.y) + v5 * up2(u5.y) + v6 * up2(u6.y) + v7 * up2(u7.y);
            a2 += v0 * up2(u0.z) + v1 * up2(u1.z) + v2 * up2(u2.z) + v3 * up2(u3.z)
                + v4 * up2(u4.z) + v5 * up2(u5.z) + v6 * up2(u6.z) + v7 * up2(u7.z);
            a3 += v0 * up2(u0.w) + v1 * up2(u1.w) + v2 * up2(u2.w) + v3 * up2(u3.w)
                + v4 * up2(u4.w) + v5 * up2(u5.w) + v6 * up2(u6.w) + v7 * up2(u7.w);
        } else {
            a0 += (up2(u0.x) + up2(u1.x)) + (up2(u2.x) + up2(u3.x))
                + (up2(u4.x) + up2(u5.x)) + (up2(u6.x) + up2(u7.x));
            a1 += (up2(u0.y) + up2(u1.y)) + (up2(u2.y) + up2(u3.y))
                + (up2(u4.y) + up2(u5.y)) + (up2(u6.y) + up2(u7.y));
            a2 += (up2(u0.z) + up2(u1.z)) + (up2(u2.z) + up2(u3.z))
                + (up2(u4.z) + up2(u5.z)) + (up2(u6.z) + up2(u7.z));
            a3 += (up2(u0.w) + up2(u1.w)) + (up2(u2.w) + up2(u3.w))
                + (up2(u4.w) + up2(u5.w)) + (up2(u6.w) + up2(u7.w));
        }
    }
    uint4 o;
    o.x = (uint32_t)f2bf(a0.x) | ((uint32_t)f2bf(a0.y) << 16);
    o.y = (uint32_t)f2bf(a1.x) | ((uint32_t)f2bf(a1.y) << 16);
    o.z = (uint32_t)f2bf(a2.x) | ((uint32_t)f2bf(a2.y) << 16);
    o.w = (uint32_t)f2bf(a3.x) | ((uint32_t)f2bf(a3.y) << 16);
    outp[(size_t)orow * 16 + c16] = o;
}

// ---------------- fused GEMM, both graphs, 256 rows/block; COMPACT for L3 ----------------
template<int COMPACT>
__global__ __launch_bounds__(256) void gemm2_k(const ushort* __restrict__ AR,
                                               const ushort* __restrict__ AW,
                                               const ushort* __restrict__ wsR,
                                               const ushort* __restrict__ wsW,
                                               const float* __restrict__ rci,
                                               const float* __restrict__ rcj,
                                               const float* __restrict__ wci,
                                               const float* __restrict__ wcj,
                                               const int* __restrict__ list,
                                               const int* __restrict__ nselp,
                                               ushort* __restrict__ outR,
                                               ushort* __restrict__ outW,
                                               int mode) {
    const int halfBlocks = COMPACT ? (CAPC / GR) : ((NNODE + GR - 1) / GR);
    int graph = blockIdx.x >= halfBlocks;
    int bb = graph ? blockIdx.x - halfBlocks : blockIdx.x;
    int nrows = COMPACT ? nselp[0] : NNODE;
    const ushort* A = graph ? AW : AR;
    const ushort* wsm = graph ? wsW : wsR;
    const float* ci = graph ? wci : rci;
    const float* cj = graph ? wcj : rcj;
    ushort* outB = graph ? outW : outR;

    __shared__ ushort wt[32768];   // 64 KB: hi + lo plane, pre-swizzled
    {
        const uint4* g = (const uint4*)wsm;
        uint4* l = (uint4*)wt;
        for (int i = threadIdx.x; i < 4096; i += 256) l[i] = g[i];
    }
    __syncthreads();

    int wid = threadIdx.x >> 6, lane = threadIdx.x & 63;
    int q = lane >> 4, l16 = lane & 15;
    int rbase = bb * GR + wid * 64;
    if (rbase >= nrows) return;

    short8 z8 = {0, 0, 0, 0, 0, 0, 0, 0};
    short8 afr[4][4];
    #pragma unroll
    for (int t = 0; t < 4; ++t) {
        int row = rbase + t * 16 + l16;
        bool rok = row < nrows;
        const short8* ar = (const short8*)(A + (size_t)row * KDIM);
        #pragma unroll
        for (int kb = 0; kb < 4; ++kb)
            afr[t][kb] = rok ? ar[kb * 4 + q] : z8;
    }
    float scal[4][4];
    #pragma unroll
    for (int t = 0; t < 4; ++t)
        #pragma unroll
        for (int b = 0; b < 4; ++b) {
            int r = rbase + t * 16 + q * 4 + b;
            bool ok = r < nrows;
            int node = COMPACT ? (ok ? list[r] : 0) : r;
            scal[t][b] = ok ? (mode ? ci[node] * cj[node] : ci[node]) : 0.f;
        }

    #pragma unroll
    for (int cb = 0; cb < 8; ++cb) {
        int c = cb * 16 + l16;
        short8 bHi[4], bLo[4];
        #pragma unroll
        for (int kb = 0; kb < 4; ++kb) {
            int byte = (c * 256 + 2 * (kb * 32 + q * 8)) ^ ((c & 7) << 4);
            bHi[kb] = *(const short8*)((const char*)wt + byte);
            bLo[kb] = *(const short8*)((const char*)wt + 32768 + byte);
        }
        #pragma unroll
        for (int t = 0; t < 4; ++t) {
            f32x4 acc = {0.f, 0.f, 0.f, 0.f};
            #pragma unroll
            for (int kb = 0; kb < 4; ++kb) {
                acc = __builtin_amdgcn_mfma_f32_16x16x32_bf16(afr[t][kb], bHi[kb], acc, 0, 0, 0);
                acc = __builtin_amdgcn_mfma_f32_16x16x32_bf16(afr[t][kb], bLo[kb], acc, 0, 0, 0);
            }
            #pragma unroll
            for (int b = 0; b < 4; ++b) {
                int r = rbase + t * 16 + q * 4 + b;
                if (r < nrows)
                    outB[(size_t)r * KDIM + c] = f2bf(acc[b] * scal[t][b]);
            }
        }
    }
}

// ---------------- output assembly (compacted w1c/w2c bf16 -> f32 out) ----------------
__global__ void out_k(const ushort* __restrict__ w1c, const ushort* __restrict__ w2c,
                      const int* __restrict__ inv,
                      const float* __restrict__ disc, const float* __restrict__ kn,
                      const int* __restrict__ sid, const int* __restrict__ eid,
                      float* __restrict__ out) {
    const int total = 2 * BATCH * KDIM + BATCH + KDIM * KDIM;
    for (int i = blockIdx.x * blockDim.x + threadIdx.x; i < total;
         i += gridDim.x * blockDim.x) {
        if (i < BATCH * KDIM) {
            int b = i >> 7, c = i & 127;
            size_t r = (size_t)inv[sid[b]];
            out[i] = bf2f(w1c[r * KDIM + c]) + bf2f(w2c[r * KDIM + c]);
        } else if (i < 2 * BATCH * KDIM) {
            int j = i - BATCH * KDIM;
            int b = j >> 7, c = j & 127;
            size_t r = (size_t)inv[S_NUM + eid[b]];
            out[i] = bf2f(w1c[r * KDIM + c]) + bf2f(w2c[r * KDIM + c]);
        } else if (i < 2 * BATCH * KDIM + BATCH) {
            out[i] = disc[eid[i - 2 * BATCH * KDIM]];
        } else {
            out[i] = kn[i - (2 * BATCH * KDIM + BATCH)];
        }
    }
}

static inline size_t align_up(size_t x) { return (x + 255) & ~(size_t)255; }

extern "C" void kernel_launch(void* const* d_in, const int* in_sizes, int n_in,
                              void* d_out, int out_size, void* d_ws, size_t ws_size,
                              hipStream_t stream) {
    const float* stu  = (const float*)d_in[0];
    const float* exer = (const float*)d_in[1];
    const float* kn   = (const float*)d_in[2];
    const float* disc = (const float*)d_in[3];
    const float* rW   = (const float*)d_in[4];
    const float* wW   = (const float*)d_in[5];
    const float* rci  = (const float*)d_in[6];
    const float* rcj  = (const float*)d_in[7];
    const float* wci  = (const float*)d_in[8];
    const float* wcj  = (const float*)d_in[9];
    const int* redge   = (const int*)d_in[10];
    const int* wedge   = (const int*)d_in[11];
    const int* sid     = (const int*)d_in[12];
    const int* eid     = (const int*)d_in[13];
    float* out         = (float*)d_out;

    char* p = (char*)d_ws;
    const size_t fB16 = align_up((size_t)(NNODE + 1) * KDIM * 2);   // +sentinel row
    ushort* featb = (ushort*)p; p += fB16;  // L1 gather src; later w1c/w2c (compact, 8MB)
    ushort* fcR = (ushort*)p; p += fB16;
    ushort* fcW = (ushort*)p; p += fB16;
    ushort* pR  = (ushort*)p; p += fB16;    // agg out; aliases buckets pre-L1
    ushort* pW  = (ushort*)p; p += fB16;
    ushort* ws  = (ushort*)p; p += align_up((size_t)6 * 32768 * 2);   // 384 KB
    int* gbcnt = (int*)p; p += align_up((size_t)256 * 4);
    int* rpb = (int*)p; p += align_up((size_t)2 * NNODE * 4);
    int* rpe = (int*)p; p += align_up((size_t)2 * NNODE * 4);
    int* csr = (int*)p; p += align_up((size_t)256 * RCAP * 4);
    float* cjpR = (float*)p; p += align_up((size_t)(NNODE + 1) * 4);
    float* cjpW = (float*)p; p += align_up((size_t)(NNODE + 1) * 4);
    int* flags = (int*)p; p += align_up((size_t)NNODE * 4);
    int* list  = (int*)p; p += align_up((size_t)CAPC * 4);
    int* inv   = (int*)p; p += align_up((size_t)NNODE * 4);
    int* nsel  = (int*)p; p += align_up((size_t)16 * 4);
    // buckets alias pR (256 x 8448 x 4B = 8.65 MB < 17.92 MB)
    uint32_t* bpk = (uint32_t*)pR;
    // compact outputs alias featb (2 x 16384 x 128 x 2B = 8 MB < 17.92 MB)
    ushort* w1c = featb;
    ushort* w2c = featb + (size_t)CAPC * KDIM;

    const int aggFull = (2 * NNODE + 15) / 16;      // 8750
    const int aggComp = 2 * CAPC / 16;              // 2048
    const int gemmFull = 2 * ((NNODE + GR - 1) / GR);
    const int gemmComp = 2 * (CAPC / GR);
    const int NB = (NEDGE + CHUNK - 1) / CHUNK;

    // ---- shared prep ----
    prepW_k<<<(6 * 16384 + 255) / 256, 256, 0, stream>>>(rW, wW, ws, gbcnt, flags, nsel);
    bucket_k<<<2 * NB, 256, 0, stream>>>(redge, wedge, gbcnt, bpk);
    build_k<<<256, 256, 0, stream>>>(bpk, gbcnt, rpb, rpe, csr);
    mark_k<<<(2 * BATCH + 255) / 256, 256, 0, stream>>>(sid, eid, flags);
    compact_k<<<(NNODE + 255) / 256, 256, 0, stream>>>(flags, list, inv, nsel);
    cvt1_k<<<2048, 256, 0, stream>>>(stu, exer, rcj, wcj, (uint4*)featb,
                                     (uint4*)fcR, (uint4*)fcW, cjpR, cjpW);

    // ---- L1 (full) ----
    agg2_k<1, 0><<<aggFull, 256, 0, stream>>>((const uint4*)featb, (const uint4*)featb,
                                              cjpR, cjpW, rpb, rpe, csr, nullptr, nullptr,
                                              (uint4*)pR, (uint4*)pW);
    gemm2_k<0><<<gemmFull, 256, 0, stream>>>(pR, pW, ws + 0 * 32768, ws + 3 * 32768,
                                             rci, rcj, wci, wcj, nullptr, nullptr,
                                             fcR, fcW, 1);
    // ---- L2 (full) ----
    agg2_k<0, 0><<<aggFull, 256, 0, stream>>>((const uint4*)fcR, (const uint4*)fcW,
                                              nullptr, nullptr, rpb, rpe, csr,
                                              nullptr, nullptr, (uint4*)pR, (uint4*)pW);
    gemm2_k<0><<<gemmFull, 256, 0, stream>>>(pR, pW, ws + 1 * 32768, ws + 4 * 32768,
                                             rci, rcj, wci, wcj, nullptr, nullptr,
                                             fcR, fcW, 1);
    // ---- L3 (compact: only nodes the output reads) ----
    agg2_k<0, 1><<<aggComp, 256, 0, stream>>>((const uint4*)fcR, (const uint4*)fcW,
                                              nullptr, nullptr, rpb, rpe, csr,
                                              list, nsel, (uint4*)pR, (uint4*)pW);
    gemm2_k<1><<<gemmComp, 256, 0, stream>>>(pR, pW, ws + 2 * 32768, ws + 5 * 32768,
                                             rci, rcj, wci, wcj, list, nsel,
                                             w1c, w2c, 0);

    out_k<<<2048, 256, 0, stream>>>(w1c, w2c, inv, disc, kn, sid, eid, out);
}